// Round 8
// baseline (156.477 us; speedup 1.0000x reference)
//
#include <hip/hip_runtime.h>
#include <math.h>

// Problem dims (fixed by reference)
#define BD   4
#define TD   8
#define CD   32
#define WD   40
#define KD   9       // final top-k
#define HWD  1600
#define TM1  7       // T-1
#define NPAIR (BD * TM1)
#define OUTK ((size_t)NPAIR * HWD * KD)   // 403200
#define CL   6       // per-class sorted-column length (4 columns per lane)
#define NEX  12      // candidates per (i, gr, half) sorted list

// d_ws layout (bytes)
#define FNW_OFF   0                        // bf16 normalized, [bt][node][16 uints] = 3.2768 MB
#define TRAW_OFF  3276800                  // raw f32 node-major, [bt][node][32]   = 6.5536 MB
#define RND_OFF   9830400                  // f64 inv-norms, [bt][node]            = 0.4096 MB
#define CAND_OFF  10240000                 // u32 cand lists [pair][i][gr][half][12] = 17.2 MB

typedef __attribute__((ext_vector_type(8))) short short8;   // 8 bf16 (4 VGPRs)
typedef __attribute__((ext_vector_type(4))) float f32x4;

__device__ __forceinline__ uint f2bf(float f) {             // f32 -> bf16 bits (RNE)
    uint u = __float_as_uint(f);
    return (u + 0x7FFFu + ((u >> 16) & 1u)) >> 16;
}

// ------- kernel 1: normalize+transpose, coalesced reads -------
// block = 256 thr = 4 waves; wave q handles channels [8q,8q+8) of 64 nodes.
// Reads x[(q*8+cc)*HWD + n0 + lane]: 256 B contiguous per wave-load.
__global__ __launch_bounds__(256)
void prep_kernel(const float* __restrict__ x, uint* __restrict__ fnw,
                 float* __restrict__ traw, double* __restrict__ rnd)
{
    __shared__ double s_ssd[4][64];

    const int tid = threadIdx.x;
    const int q   = tid >> 6;          // wave id = channel group
    const int l   = tid & 63;
    const int bt  = blockIdx.x / 25;
    const int nb  = blockIdx.x - bt * 25;
    const int node = nb * 64 + l;

    const float* src = x + (size_t)bt * CD * HWD + node;
    float v[8];
    double ssd = 0.0;
#pragma unroll
    for (int cc = 0; cc < 8; ++cc) {
        const float a = src[(size_t)(q * 8 + cc) * HWD];   // coalesced
        v[cc] = a;
        ssd = fma((double)a, (double)a, ssd);
    }
    s_ssd[q][l] = ssd;
    __syncthreads();
    const double tot = s_ssd[0][l] + s_ssd[1][l] + s_ssd[2][l] + s_ssd[3][l];
    const double rv  = 1.0 / sqrt(tot + 1e-8);
    if (q == 0) rnd[(size_t)bt * HWD + node] = rv;
    const float rn = (float)rv;

    uint* dstb = fnw + (size_t)(bt * HWD + node) * 16 + q * 4;
    const uint w0 = f2bf(v[0]*rn) | (f2bf(v[1]*rn) << 16);
    const uint w1 = f2bf(v[2]*rn) | (f2bf(v[3]*rn) << 16);
    const uint w2 = f2bf(v[4]*rn) | (f2bf(v[5]*rn) << 16);
    const uint w3 = f2bf(v[6]*rn) | (f2bf(v[7]*rn) << 16);
    *(uint4*)dstb = make_uint4(w0, w1, w2, w3);

    float* dstr = traw + (size_t)(bt * HWD + node) * 32 + q * 8;
    ((float4*)dstr)[0] = make_float4(v[0], v[1], v[2], v[3]);
    ((float4*)dstr)[1] = make_float4(v[4], v[5], v[6], v[7]);
}

// ------- kernel 2: scan only — MFMA + per-class sorted columns + 12-pop dump -------
// VGPR-lean (no phase-2 state): target <=64 regs -> 8 waves/SIMD, all 5600 waves
// resident, no tail. Arithmetic identical to R7's scan. Ring-2 prefetch.
__global__ __launch_bounds__(256)
void scan_kernel(const uint* __restrict__ fnw, uint* __restrict__ cand)
{
    const int tid  = threadIdx.x;
    const int lane = tid & 63;
    const int wid  = tid >> 6;
    const int li   = lane & 15;
    const int gr   = lane >> 4;          // 0..3
    const int iq   = wid & 1;
    const int half = wid >> 1;

    // bijective XCD swizzle of 1400 blocks (1400 % 8 == 0)
    const int bid  = blockIdx.x;
    const int xcd  = bid & 7;
    const int kk   = bid >> 3;
    const int work = xcd * 175 + kk;
    const int f    = work / 50;
    const int rem  = work - f * 50;
    const int b    = f / TM1;
    const int t    = f - b * TM1;
    const int i    = rem * 32 + iq * 16 + li;

    const uint* fA = fnw + (size_t)(b * TD + t)     * HWD * 16;   // frame t  (B op)
    const uint* fB = fnw + (size_t)(b * TD + t + 1) * HWD * 16;   // frame t+1 (A op)

    const short8 bF = *(const short8*)(fA + (size_t)i * 16 + gr * 4);

    uint C[4][CL];
#pragma unroll
    for (int r = 0; r < 4; ++r)
#pragma unroll
        for (int k = 0; k < CL; ++k) C[r][k] = 0u;

    int jr[4];
#pragma unroll
    for (int r = 0; r < 4; ++r) jr[r] = 2047 - half * 800 - 4 * gr - r;

    const f32x4 one4 = {1.f, 1.f, 1.f, 1.f};   // acc = 1 + sim >= 0 -> uint-monotonic

#define LDT(dst, s) dst = *(const short8*)(fB + (size_t)((s) * 16 + li) * 16 + gr * 4)

#define INSTILE(acc) do {                                              \
    _Pragma("unroll")                                                  \
    for (int r = 0; r < 4; ++r) {                                      \
        int ub = __float_as_int((acc)[r]);                             \
        ub = ub < 0 ? 0 : ub;                                          \
        uint u = ((uint)ub & 0xFFFFF800u) | (uint)jr[r];               \
        uint tv = u;                                                   \
        _Pragma("unroll")                                              \
        for (int k = 0; k < CL; ++k) {                                 \
            const uint lo = min(C[r][k], tv);                          \
            C[r][k] = max(C[r][k], tv);                                \
            tv = lo;                                                   \
        }                                                              \
        jr[r] -= 16;                                                   \
    }                                                                  \
} while (0)

    const int s0 = half * 50;
    short8 a0, a1;
    LDT(a0, s0); LDT(a1, s0 + 1);

    // 23 iterations cover tiles s0..s0+45; loads run 2 tiles ahead
    for (int sb = s0; sb < s0 + 46; sb += 2) {
        f32x4 acc;
        acc = __builtin_amdgcn_mfma_f32_16x16x32_bf16(a0, bF, one4, 0, 0, 0);
        LDT(a0, sb + 2);
        INSTILE(acc);
        acc = __builtin_amdgcn_mfma_f32_16x16x32_bf16(a1, bF, one4, 0, 0, 0);
        LDT(a1, sb + 3);
        INSTILE(acc);
    }
    // tail: tiles s0+46..49
    {
        f32x4 acc;
        acc = __builtin_amdgcn_mfma_f32_16x16x32_bf16(a0, bF, one4, 0, 0, 0);
        LDT(a0, s0 + 48);
        INSTILE(acc);
        acc = __builtin_amdgcn_mfma_f32_16x16x32_bf16(a1, bF, one4, 0, 0, 0);
        LDT(a1, s0 + 49);
        INSTILE(acc);
        acc = __builtin_amdgcn_mfma_f32_16x16x32_bf16(a0, bF, one4, 0, 0, 0);
        INSTILE(acc);
        acc = __builtin_amdgcn_mfma_f32_16x16x32_bf16(a1, bF, one4, 0, 0, 0);
        INSTILE(acc);
    }
#undef LDT
#undef INSTILE

    // ---- extract sorted top-NEX (descending packed), stream to cand ----
    uint* cp = cand + (((size_t)f * HWD + i) * 8 + gr * 2 + half) * NEX;
#pragma unroll
    for (int rd = 0; rd < NEX; ++rd) {
        const uint m = max(max(C[0][0], C[1][0]), max(C[2][0], C[3][0]));
#pragma unroll
        for (int r = 0; r < 4; ++r) {
            const bool e = (C[r][0] == m);
#pragma unroll
            for (int k = 0; k < CL - 1; ++k) C[r][k] = e ? C[r][k + 1] : C[r][k];
            C[r][CL - 1] = e ? 0u : C[r][CL - 1];
        }
        cp[rd] = m;
    }
}

// ------- kernel 3: f64 re-rank + tournament + outputs (R7 phase-2, lists from ws) ----
// lane (li, gr) of wave -> i = ib*64 + wid*16 + li, gr's j-subset; 700 blocks.
__global__ __launch_bounds__(256)
void rerank_kernel(const float* __restrict__ traw, const double* __restrict__ rnd,
                   const uint* __restrict__ cand, float* __restrict__ out)
{
    const int tid  = threadIdx.x;
    const int lane = tid & 63;
    const int wid  = tid >> 6;
    const int li   = lane & 15;
    const int gr   = lane >> 4;
    const int bid  = blockIdx.x;
    const int f    = bid / 25;
    const int ib   = bid - f * 25;
    const int b    = f / TM1;
    const int t    = f - b * TM1;
    const int bt0  = b * TD + t;
    const int bt1  = bt0 + 1;
    const int i    = ib * 64 + wid * 16 + li;

    // load the two sorted-12 lists for (i, gr)
    const uint* cp = cand + (((size_t)f * HWD + i) * 8 + gr * 2) * NEX;
    uint sA[NEX], sB[NEX];
#pragma unroll
    for (int q = 0; q < 3; ++q) {
        const uint4 va = *(const uint4*)(cp + q * 4);
        sA[q*4+0] = va.x; sA[q*4+1] = va.y; sA[q*4+2] = va.z; sA[q*4+3] = va.w;
        const uint4 vb = *(const uint4*)(cp + NEX + q * 4);
        sB[q*4+0] = vb.x; sB[q*4+1] = vb.y; sB[q*4+2] = vb.z; sB[q*4+3] = vb.w;
    }

    const float* tA = traw + (size_t)bt0 * HWD * 32 + (size_t)i * 32;
    float arf[CD];
#pragma unroll
    for (int q = 0; q < 8; ++q) {
        const float4 r4 = ((const float4*)tA)[q];
        arf[4*q+0] = r4.x; arf[4*q+1] = r4.y; arf[4*q+2] = r4.z; arf[4*q+3] = r4.w;
    }
    const double rna = rnd[(size_t)bt0 * HWD + i];
    const float*  trB = traw + (size_t)bt1 * HWD * 32;
    const double* rnB = rnd + (size_t)bt1 * HWD;

    double fv[KD]; int fi[KD];
#pragma unroll
    for (int k = 0; k < KD; ++k) { fv[k] = -1.0e300; fi[k] = 0; }

    for (int rd = 0; rd < NEX; ++rd) {
        // pop global max of the two sorted lists (packed values unique)
        const bool tAh = sA[0] > sB[0];
        const uint m = tAh ? sA[0] : sB[0];
#pragma unroll
        for (int k = 0; k < NEX - 1; ++k) {
            sA[k] = tAh ? sA[k + 1] : sA[k];
            sB[k] = tAh ? sB[k] : sB[k + 1];
        }
        const int j = 2047 - (int)(m & 2047u);
        const float4* rb = (const float4*)(trB + (size_t)j * 32);
        double d0 = 0.0, d1 = 0.0, d2 = 0.0, d3 = 0.0;
#pragma unroll
        for (int q = 0; q < 8; ++q) {
            const float4 r4 = rb[q];
            d0 = fma((double)arf[4*q+0], (double)r4.x, d0);
            d1 = fma((double)arf[4*q+1], (double)r4.y, d1);
            d2 = fma((double)arf[4*q+2], (double)r4.z, d2);
            d3 = fma((double)arf[4*q+3], (double)r4.w, d3);
        }
        const double val = ((d0 + d1) + (d2 + d3)) * rna * rnB[j];
        if (val > fv[KD - 1]) {          // desc packed order => stable tie order
            bool bg[KD];
#pragma unroll
            for (int k = 0; k < KD; ++k) bg[k] = val > fv[k];
#pragma unroll
            for (int k = KD - 1; k >= 1; --k) {
                fv[k] = bg[k - 1] ? fv[k - 1] : (bg[k] ? val : fv[k]);
                fi[k] = bg[k - 1] ? fi[k - 1] : (bg[k] ? j : fi[k]);
            }
            if (bg[0]) { fv[0] = val; fi[0] = j; }
        }
    }

    // ---- 4-way sorted-list tournament merge across the i-group (lanes l^16, l^32) ----
    double w9v[KD]; int w9j[KD];
#pragma unroll
    for (int rd = 0; rd < KD; ++rd) {
        double hv = fv[0]; int hj = fi[0];
        {
            const double ov = __shfl_xor(hv, 16); const int oj = __shfl_xor(hj, 16);
            const bool tk = (ov > hv) || (ov == hv && oj < hj);
            hv = tk ? ov : hv; hj = tk ? oj : hj;
        }
        {
            const double ov = __shfl_xor(hv, 32); const int oj = __shfl_xor(hj, 32);
            const bool tk = (ov > hv) || (ov == hv && oj < hj);
            hv = tk ? ov : hv; hj = tk ? oj : hj;
        }
        w9v[rd] = hv; w9j[rd] = hj;
        const bool win = (fi[0] == hj);
#pragma unroll
        for (int k = 0; k < KD - 1; ++k) {
            fv[k] = win ? fv[k + 1] : fv[k];
            fi[k] = win ? fi[k + 1] : fi[k];
        }
        if (win) fv[KD - 1] = -1.0e300;
    }

    // ---- outputs: all 4 group lanes hold identical winners; split the stores ----
    double wsum = 0.0;
#pragma unroll
    for (int k = 0; k < KD; ++k) wsum += w9v[k];
    const double winv = 1.0 / (wsum + 1e-8);

    const size_t base = ((size_t)f * HWD + i) * KD;
    const int sy = i / WD, sx = i - sy * WD;
    if (gr == 0) {
#pragma unroll
        for (int k = 0; k < KD; ++k) out[base + k] = (float)(w9v[k] * winv);
    } else if (gr == 1) {
#pragma unroll
        for (int k = 0; k < KD; ++k) out[OUTK + base + k] = (float)w9j[k];
    } else if (gr == 2) {
#pragma unroll
        for (int k = 0; k < KD; ++k) {
            const int j = w9j[k];
            out[2 * OUTK + (base + k) * 2 + 0] = (float)(j / WD - sy);
        }
    } else {
#pragma unroll
        for (int k = 0; k < KD; ++k) {
            const int j = w9j[k];
            out[2 * OUTK + (base + k) * 2 + 1] = (float)(j - (j / WD) * WD - sx);
        }
    }
}

extern "C" void kernel_launch(void* const* d_in, const int* in_sizes, int n_in,
                              void* d_out, int out_size, void* d_ws, size_t ws_size,
                              hipStream_t stream)
{
    const float* x = (const float*)d_in[0];
    uint*   fnw  = (uint*)((char*)d_ws + FNW_OFF);
    float*  traw = (float*)((char*)d_ws + TRAW_OFF);
    double* rnd  = (double*)((char*)d_ws + RND_OFF);
    uint*   cand = (uint*)((char*)d_ws + CAND_OFF);
    float*  out  = (float*)d_out;

    prep_kernel<<<dim3(BD * TD * 25), 256, 0, stream>>>(x, fnw, traw, rnd);
    scan_kernel<<<dim3(NPAIR * 50), 256, 0, stream>>>(fnw, cand);
    rerank_kernel<<<dim3(NPAIR * 25), 256, 0, stream>>>(traw, rnd, cand, out);
}